// Round 1
// baseline (283.554 us; speedup 1.0000x reference)
//
#include <hip/hip_runtime.h>

#define EPS_LN 1e-5f
#define EPS_D  1e-8f

// ---------------------------------------------------------------------------
// Kernel 1: Y[N,256] = LayerNorm(X[N,256]; g, bln) @ W[256,256] + bias[256]
// block = 256 threads (4 waves), BM = 32 rows per block.
// LN phase: each wave handles 8 rows (float4 loads, shfl reduction).
// GEMM phase: thread t owns column t; x broadcast from LDS (uniform addr),
// W streamed coalesced from L2.
// ---------------------------------------------------------------------------
__global__ __launch_bounds__(256) void ln_gemm_kernel(
    const float* __restrict__ X, const float* __restrict__ g,
    const float* __restrict__ bln, const float* __restrict__ W,
    const float* __restrict__ bias, float* __restrict__ Y)
{
    __shared__ float xln[32][260];   // 260 = 256 + 4 pad (keeps float4 alignment)

    const int tid  = threadIdx.x;
    const int lane = tid & 63;
    const int wave = tid >> 6;
    const int row0 = blockIdx.x * 32;

    // g/b for this lane's 4 columns (cols lane*4 .. lane*4+3)
    const float4 g4 = ((const float4*)g)[lane];
    const float4 b4 = ((const float4*)bln)[lane];

    // ---- LayerNorm: wave w handles rows w*8 .. w*8+7 ----
    #pragma unroll
    for (int rr = 0; rr < 8; ++rr) {
        const int r = wave * 8 + rr;
        float4 v = ((const float4*)X)[(size_t)(row0 + r) * 64 + lane];
        float s  = v.x + v.y + v.z + v.w;
        float ss = v.x*v.x + v.y*v.y + v.z*v.z + v.w*v.w;
        #pragma unroll
        for (int off = 1; off < 64; off <<= 1) {
            s  += __shfl_xor(s,  off);
            ss += __shfl_xor(ss, off);
        }
        const float mu   = s * (1.0f / 256.0f);
        const float var  = ss * (1.0f / 256.0f) - mu * mu;
        const float rstd = rsqrtf(var + EPS_LN);
        float4 o;
        o.x = (v.x - mu) * rstd * g4.x + b4.x;
        o.y = (v.y - mu) * rstd * g4.y + b4.y;
        o.z = (v.z - mu) * rstd * g4.z + b4.z;
        o.w = (v.w - mu) * rstd * g4.w + b4.w;
        *(float4*)&xln[r][lane * 4] = o;
    }
    __syncthreads();

    // ---- GEMM: thread owns column c = tid, accumulates 32 rows ----
    const int c = tid;
    float acc[32];
    #pragma unroll
    for (int r = 0; r < 32; ++r) acc[r] = 0.0f;

    for (int k0 = 0; k0 < 256; k0 += 4) {
        const float w0 = W[(size_t)(k0 + 0) * 256 + c];
        const float w1 = W[(size_t)(k0 + 1) * 256 + c];
        const float w2 = W[(size_t)(k0 + 2) * 256 + c];
        const float w3 = W[(size_t)(k0 + 3) * 256 + c];
        #pragma unroll
        for (int r = 0; r < 32; ++r) {
            const float4 xv = *(const float4*)&xln[r][k0];   // wave-uniform addr -> broadcast
            float a = acc[r];
            a = fmaf(xv.x, w0, a);
            a = fmaf(xv.y, w1, a);
            a = fmaf(xv.z, w2, a);
            a = fmaf(xv.w, w3, a);
            acc[r] = a;
        }
    }

    const float bv = bias[c];
    #pragma unroll
    for (int r = 0; r < 32; ++r)
        Y[(size_t)(row0 + r) * 256 + c] = acc[r] + bv;
}

// ---------------------------------------------------------------------------
// Kernel 2: per fine point u: top-3 nearest coarse points, inverse-distance
// weights, out[u,:] += sum_k w_k * xc[idx_k,:]   (out pre-filled with xu)
// block = 256 threads (4 waves), 32 fine points per block (8 per wave),
// grid = 512 blocks. Coarse (x,y,z,|c|^2) staged in 64 KB LDS.
// ---------------------------------------------------------------------------
__device__ __forceinline__ bool tb_lt(float da, int ia, float db, int ib) {
    return (da < db) || (da == db && ia < ib);   // JAX top_k tie-break: lower idx
}

__global__ __launch_bounds__(256) void topk_interp_kernel(
    const float* __restrict__ x_pos,    // [4096][3]
    const float* __restrict__ xup_pos,  // [16384][3]
    const float* __restrict__ xc,       // [4096][256]
    float* __restrict__ out)            // [16384][256] (contains xu)
{
    __shared__ float4 cp[4096];         // (x, y, z, |c|^2) : 64 KB

    const int tid = threadIdx.x;
    for (int i = tid; i < 4096; i += 256) {
        const float px = x_pos[i * 3 + 0];
        const float py = x_pos[i * 3 + 1];
        const float pz = x_pos[i * 3 + 2];
        cp[i] = make_float4(px, py, pz, px * px + py * py + pz * pz);
    }
    __syncthreads();

    const int lane = tid & 63;
    const int wave = tid >> 6;

    for (int q = 0; q < 8; ++q) {
        const int u = blockIdx.x * 32 + wave * 8 + q;
        const float ux = xup_pos[u * 3 + 0];
        const float uy = xup_pos[u * 3 + 1];
        const float uz = xup_pos[u * 3 + 2];
        const float uu = ux * ux + uy * uy + uz * uz;

        // per-lane top-3 over coarse indices lane, 64+lane, ...
        float bd0 = 3.4e38f, bd1 = 3.4e38f, bd2 = 3.4e38f;
        int   bi0 = 0,       bi1 = 0,       bi2 = 0;

        for (int ii = 0; ii < 64; ++ii) {
            const int ci = ii * 64 + lane;
            const float4 p = cp[ci];
            const float dot = ux * p.x + uy * p.y + uz * p.z;
            const float d   = (uu - 2.0f * dot) + p.w;   // matches reference formula
            const bool lt2 = d < bd2;
            const bool lt1 = d < bd1;
            const bool lt0 = d < bd0;
            const float nd2 = lt1 ? bd1 : (lt2 ? d : bd2);
            const int   ni2 = lt1 ? bi1 : (lt2 ? ci : bi2);
            const float nd1 = lt0 ? bd0 : (lt1 ? d : bd1);
            const int   ni1 = lt0 ? bi0 : (lt1 ? ci : bi1);
            bd0 = lt0 ? d : bd0;  bi0 = lt0 ? ci : bi0;
            bd1 = nd1;            bi1 = ni1;
            bd2 = nd2;            bi2 = ni2;
        }

        // butterfly merge of per-lane top-3 lists (all lanes converge)
        #pragma unroll
        for (int m = 1; m < 64; m <<= 1) {
            const float od[3] = { __shfl_xor(bd0, m), __shfl_xor(bd1, m), __shfl_xor(bd2, m) };
            const int   oi[3] = { __shfl_xor(bi0, m), __shfl_xor(bi1, m), __shfl_xor(bi2, m) };
            #pragma unroll
            for (int e = 0; e < 3; ++e) {
                const float d  = od[e];
                const int   ci = oi[e];
                const bool lt2 = tb_lt(d, ci, bd2, bi2);
                const bool lt1 = tb_lt(d, ci, bd1, bi1);
                const bool lt0 = tb_lt(d, ci, bd0, bi0);
                const float nd2 = lt1 ? bd1 : (lt2 ? d : bd2);
                const int   ni2 = lt1 ? bi1 : (lt2 ? ci : bi2);
                const float nd1 = lt0 ? bd0 : (lt1 ? d : bd1);
                const int   ni1 = lt0 ? bi0 : (lt1 ? ci : bi1);
                bd0 = lt0 ? d : bd0;  bi0 = lt0 ? ci : bi0;
                bd1 = nd1;            bi1 = ni1;
                bd2 = nd2;            bi2 = ni2;
            }
        }

        // inverse-distance weights (reference: w = 1/(d2+eps), normalized)
        float w0 = 1.0f / (bd0 + EPS_D);
        float w1 = 1.0f / (bd1 + EPS_D);
        float w2 = 1.0f / (bd2 + EPS_D);
        const float wsum = w0 + w1 + w2;
        w0 /= wsum; w1 /= wsum; w2 /= wsum;

        // gather + weighted sum + add (4 cols per lane, float4)
        const float4 a0 = ((const float4*)(xc + (size_t)bi0 * 256))[lane];
        const float4 a1 = ((const float4*)(xc + (size_t)bi1 * 256))[lane];
        const float4 a2 = ((const float4*)(xc + (size_t)bi2 * 256))[lane];
        float4* op = (float4*)(out + (size_t)u * 256);
        float4 o = op[lane];
        o.x += w0 * a0.x + w1 * a1.x + w2 * a2.x;
        o.y += w0 * a0.y + w1 * a1.y + w2 * a2.y;
        o.z += w0 * a0.z + w1 * a1.z + w2 * a2.z;
        o.w += w0 * a0.w + w1 * a1.w + w2 * a2.w;
        op[lane] = o;
    }
}

// ---------------------------------------------------------------------------
extern "C" void kernel_launch(void* const* d_in, const int* in_sizes, int n_in,
                              void* d_out, int out_size, void* d_ws, size_t ws_size,
                              hipStream_t stream)
{
    const float* x_feat   = (const float*)d_in[0];   // [4096, 256]
    const float* x_pos    = (const float*)d_in[1];   // [4096, 3]
    const float* xup_feat = (const float*)d_in[2];   // [16384, 256]
    const float* xup_pos  = (const float*)d_in[3];   // [16384, 3]
    const float* g1       = (const float*)d_in[4];
    const float* b1       = (const float*)d_in[5];
    const float* W        = (const float*)d_in[6];   // [256, 256]
    const float* b        = (const float*)d_in[7];
    const float* g2       = (const float*)d_in[8];
    const float* b2       = (const float*)d_in[9];
    const float* W_up     = (const float*)d_in[10];  // [256, 256]
    const float* b_up     = (const float*)d_in[11];

    float* out = (float*)d_out;                      // [16384, 256]
    float* xc  = (float*)d_ws;                       // [4096, 256] = 4 MB scratch

    // coarse: LN -> GEMM -> ws
    ln_gemm_kernel<<<128, 256, 0, stream>>>(x_feat, g1, b1, W, b, xc);
    // fine: LN -> GEMM -> out (this IS xu; interp gets added on top)
    ln_gemm_kernel<<<512, 256, 0, stream>>>(xup_feat, g2, b2, W_up, b_up, out);
    // top-3 + inverse-distance interp + add
    topk_interp_kernel<<<512, 256, 0, stream>>>(x_pos, xup_pos, xc, out);
}

// Round 2
// 202.163 us; speedup vs baseline: 1.4026x; 1.4026x over previous
//
#include <hip/hip_runtime.h>

#define EPS_LN 1e-5f
#define EPS_D  1e-8f

typedef __attribute__((ext_vector_type(8))) short s16x8;
typedef __attribute__((ext_vector_type(4))) float f32x4;

// ---------------- ws layout (bytes) ----------------
// xc   : 4096*256*4  = 4194304   @ 0
// mu   : 20480*4     = 81920     @ 4194304   (fine rows 0..16383, coarse +16384)
// rs   : 20480*4     = 81920     @ 4276224
// cp   : 4096*16     = 65536     @ 4358144   (x,y,z,|c|^2)
// wth  : 256*256*2   = 131072    @ 4423680   (W^T  hi bf16)
// wtl  :                         @ 4554752   (W^T  lo bf16)
// wuth :                         @ 4685824   (W_up^T hi)
// wutl :                         @ 4816896   (W_up^T lo)   total ~4.95 MB
#define XC_OFF   0u
#define MU_OFF   4194304u
#define RS_OFF   4276224u
#define CP_OFF   4358144u
#define WTH_OFF  4423680u
#define WTL_OFF  4554752u
#define WUTH_OFF 4685824u
#define WUTL_OFF 4816896u

// ---------------------------------------------------------------------------
// prep: (a) LN row stats for fine(16384)+coarse(4096) rows
//       (b) W, W_up -> transposed bf16 hi/lo planes (truncation split)
//       (c) coarse pos -> (x,y,z,|c|^2)
// ---------------------------------------------------------------------------
__global__ __launch_bounds__(256) void prep_kernel(
    const float* __restrict__ x_feat, const float* __restrict__ xup_feat,
    const float* __restrict__ x_pos,
    const float* __restrict__ W, const float* __restrict__ W_up,
    float* __restrict__ mu, float* __restrict__ rs, float4* __restrict__ cp,
    unsigned short* __restrict__ wth, unsigned short* __restrict__ wtl,
    unsigned short* __restrict__ wuth, unsigned short* __restrict__ wutl)
{
    const int bid = blockIdx.x, tid = threadIdx.x;
    const int lane = tid & 63, wave = tid >> 6;

    if (bid < 320) {
        for (int r = bid * 4 + wave; r < 20480; r += 1280) {
            const float* src = (r < 16384) ? (xup_feat + (size_t)r * 256)
                                           : (x_feat + (size_t)(r - 16384) * 256);
            const float4 v = ((const float4*)src)[lane];
            float s  = v.x + v.y + v.z + v.w;
            float ss = v.x*v.x + v.y*v.y + v.z*v.z + v.w*v.w;
            #pragma unroll
            for (int off = 1; off < 64; off <<= 1) {
                s  += __shfl_xor(s,  off);
                ss += __shfl_xor(ss, off);
            }
            if (lane == 0) {
                const float m   = s * (1.0f / 256.0f);
                const float var = ss * (1.0f / 256.0f) - m * m;
                mu[r] = m;
                rs[r] = rsqrtf(var + EPS_LN);
            }
        }
    } else if (bid < 336) {
        const int mb = bid - 320;
        const float* src = (mb < 8) ? W : W_up;
        unsigned short* dh = (mb < 8) ? wth : wuth;
        unsigned short* dl = (mb < 8) ? wtl : wutl;
        const int k  = (mb & 7) * 32 + (tid >> 3);
        const int n0 = (tid & 7) * 32;
        for (int i = 0; i < 32; i += 4) {
            const float4 v = *(const float4*)&src[(size_t)k * 256 + n0 + i];
            const float vv[4] = { v.x, v.y, v.z, v.w };
            #pragma unroll
            for (int c = 0; c < 4; ++c) {
                const unsigned ua = __float_as_uint(vv[c]);
                const unsigned hb = ua & 0xFFFF0000u;
                const float rr = vv[c] - __uint_as_float(hb);
                const size_t o = (size_t)(n0 + i + c) * 256 + k;
                dh[o] = (unsigned short)(ua >> 16);
                dl[o] = (unsigned short)(__float_as_uint(rr) >> 16);
            }
        }
    } else {
        const int i = (bid - 336) * 256 + tid;
        if (i < 4096) {
            const float px = x_pos[i * 3 + 0];
            const float py = x_pos[i * 3 + 1];
            const float pz = x_pos[i * 3 + 2];
            cp[i] = make_float4(px, py, pz, px * px + py * py + pz * pz);
        }
    }
}

// ---------------------------------------------------------------------------
// gemm: Y = LN(X) @ Wt^T + bias via bf16x2 split (hh + hl + lh MFMAs).
// block = 256 thr = 4 waves (2x2), tile 128x128, wave subtile 64x64 = 4x4
// frags of 16x16x32. All fragments loaded straight from global (L2-resident);
// LN + truncation-split fused into the A-fragment load. No LDS.
// blocks 0..255: fine (xup_feat -> d_out); 256..319: coarse (x_feat -> xc).
// ---------------------------------------------------------------------------
__global__ __launch_bounds__(256) void gemm_kernel(
    const float* __restrict__ Xf, const float* __restrict__ Xc,
    const float* __restrict__ mu, const float* __restrict__ rs,
    const float* __restrict__ g2, const float* __restrict__ b2,
    const float* __restrict__ g1, const float* __restrict__ b1,
    const unsigned short* __restrict__ wuth, const unsigned short* __restrict__ wutl,
    const unsigned short* __restrict__ wth,  const unsigned short* __restrict__ wtl,
    const float* __restrict__ b_up, const float* __restrict__ bb,
    float* __restrict__ outF, float* __restrict__ outC)
{
    const int bid = blockIdx.x;
    const float *X, *gg, *bt, *bias; const unsigned short *BH, *BL; float* OUT;
    int row0, col0, statoff;
    if (bid < 256) {
        X = Xf; gg = g2; bt = b2; BH = wuth; BL = wutl; bias = b_up; OUT = outF;
        row0 = (bid >> 1) * 128; col0 = (bid & 1) * 128; statoff = 0;
    } else {
        const int id = bid - 256;
        X = Xc; gg = g1; bt = b1; BH = wth; BL = wtl; bias = bb; OUT = outC;
        row0 = (id >> 1) * 128; col0 = (id & 1) * 128; statoff = 16384;
    }

    const int lane = threadIdx.x & 63;
    const int wave = threadIdx.x >> 6;
    const int wr = wave >> 1, wc = wave & 1;
    const int lm = lane & 15, lk = lane >> 4;   // lk = k-octet group

    int arow[4]; float amu[4], ars[4];
    #pragma unroll
    for (int mf = 0; mf < 4; ++mf) {
        arow[mf] = row0 + wr * 64 + mf * 16 + lm;
        amu[mf] = mu[statoff + arow[mf]];
        ars[mf] = rs[statoff + arow[mf]];
    }
    int ncol[4]; float bv[4];
    #pragma unroll
    for (int nf = 0; nf < 4; ++nf) {
        ncol[nf] = col0 + wc * 64 + nf * 16 + lm;
        bv[nf] = bias[ncol[nf]];
    }

    f32x4 acc[4][4];
    #pragma unroll
    for (int mf = 0; mf < 4; ++mf)
        #pragma unroll
        for (int nf = 0; nf < 4; ++nf)
            acc[mf][nf] = (f32x4){0.0f, 0.0f, 0.0f, 0.0f};

    for (int k0 = 0; k0 < 256; k0 += 32) {
        const int kb = k0 + lk * 8;
        const float4 gq0 = *(const float4*)(gg + kb);
        const float4 gq1 = *(const float4*)(gg + kb + 4);
        const float4 bq0 = *(const float4*)(bt + kb);
        const float4 bq1 = *(const float4*)(bt + kb + 4);
        const float gv[8] = { gq0.x, gq0.y, gq0.z, gq0.w, gq1.x, gq1.y, gq1.z, gq1.w };
        const float bw[8] = { bq0.x, bq0.y, bq0.z, bq0.w, bq1.x, bq1.y, bq1.z, bq1.w };

        s16x8 ah[4], al[4];
        #pragma unroll
        for (int mf = 0; mf < 4; ++mf) {
            const float* pa = X + (size_t)arow[mf] * 256 + kb;
            const float4 x0 = *(const float4*)pa;
            const float4 x1 = *(const float4*)(pa + 4);
            const float xs[8] = { x0.x, x0.y, x0.z, x0.w, x1.x, x1.y, x1.z, x1.w };
            #pragma unroll
            for (int j = 0; j < 8; ++j) {
                const float sj = ars[mf] * gv[j];
                const float tj = fmaf(-amu[mf], sj, bw[j]);
                const float a  = fmaf(xs[j], sj, tj);
                const unsigned ua = __float_as_uint(a);
                const unsigned hb = ua & 0xFFFF0000u;
                const float rr = a - __uint_as_float(hb);
                ah[mf][j] = (short)(ua >> 16);
                al[mf][j] = (short)(__float_as_uint(rr) >> 16);
            }
        }
        s16x8 bh[4], bl[4];
        #pragma unroll
        for (int nf = 0; nf < 4; ++nf) {
            const size_t o = (size_t)ncol[nf] * 256 + kb;
            bh[nf] = *(const s16x8*)(BH + o);
            bl[nf] = *(const s16x8*)(BL + o);
        }
        #pragma unroll
        for (int mf = 0; mf < 4; ++mf)
            #pragma unroll
            for (int nf = 0; nf < 4; ++nf) {
                acc[mf][nf] = __builtin_amdgcn_mfma_f32_16x16x32_bf16(ah[mf], bh[nf], acc[mf][nf], 0, 0, 0);
                acc[mf][nf] = __builtin_amdgcn_mfma_f32_16x16x32_bf16(ah[mf], bl[nf], acc[mf][nf], 0, 0, 0);
                acc[mf][nf] = __builtin_amdgcn_mfma_f32_16x16x32_bf16(al[mf], bh[nf], acc[mf][nf], 0, 0, 0);
            }
    }

    // epilogue: D row = lk*4 + q (per m89/m91-verified C/D layout), col = lm
    #pragma unroll
    for (int mf = 0; mf < 4; ++mf) {
        #pragma unroll
        for (int q = 0; q < 4; ++q) {
            const size_t ro = (size_t)(row0 + wr * 64 + mf * 16 + lk * 4 + q) * 256;
            #pragma unroll
            for (int nf = 0; nf < 4; ++nf)
                OUT[ro + ncol[nf]] = acc[mf][nf][q] + bv[nf];
        }
    }
}

// ---------------------------------------------------------------------------
// topk: one fine point per LANE; 8 waves split 4096 candidates (512 each);
// branchless sorted top-3 insert; cross-wave merge in LDS with (d,idx)
// lexicographic tie-break (indices ascend with chunk => exact ref semantics);
// then inverse-distance weights + gather + add onto out (out holds xu).
// grid = 256 blocks x 512 threads; block owns u in [bid*64, bid*64+64).
// ---------------------------------------------------------------------------
__global__ __launch_bounds__(512) void topk_kernel(
    const float4* __restrict__ cp, const float* __restrict__ xup_pos,
    const float* __restrict__ xc, float* __restrict__ out)
{
    __shared__ float pd[8][64][3];
    __shared__ int   pi[8][64][3];
    __shared__ float wsel[64][3];
    __shared__ int   isel[64][3];

    const int tid = threadIdx.x, lane = tid & 63, wave = tid >> 6;
    const int u = blockIdx.x * 64 + lane;

    const float ux = xup_pos[u * 3 + 0];
    const float uy = xup_pos[u * 3 + 1];
    const float uz = xup_pos[u * 3 + 2];
    const float uu = ux * ux + uy * uy + uz * uz;

    float b0 = 3.402823466e+38f, b1 = b0, b2 = b0;
    int i0 = 0, i1 = 0, i2 = 0;

    const int j0 = wave * 512;
    #pragma unroll 4
    for (int j = j0; j < j0 + 512; ++j) {
        const float4 c = cp[j];
        const float dot = ux * c.x + uy * c.y + uz * c.z;
        const float d = (uu - 2.0f * dot) + c.w;     // exact ref formula/order
        const bool lt0 = d < b0, lt1 = d < b1, lt2 = d < b2;
        const float n1 = lt0 ? b0 : (lt1 ? d : b1);
        const int  ni1 = lt0 ? i0 : (lt1 ? j : i1);
        const float n2 = lt1 ? b1 : (lt2 ? d : b2);
        const int  ni2 = lt1 ? i1 : (lt2 ? j : i2);
        b0 = lt0 ? d : b0;  i0 = lt0 ? j : i0;
        b1 = n1; i1 = ni1;
        b2 = n2; i2 = ni2;
    }

    pd[wave][lane][0] = b0; pd[wave][lane][1] = b1; pd[wave][lane][2] = b2;
    pi[wave][lane][0] = i0; pi[wave][lane][1] = i1; pi[wave][lane][2] = i2;
    __syncthreads();

    if (wave == 0) {
        // merge waves 1..7 into wave 0's registers (lexicographic on (d, idx))
        for (int w = 1; w < 8; ++w) {
            #pragma unroll
            for (int e = 0; e < 3; ++e) {
                const float d = pd[w][lane][e];
                const int  ci = pi[w][lane][e];
                const bool lt0 = (d < b0) || (d == b0 && ci < i0);
                const bool lt1 = (d < b1) || (d == b1 && ci < i1);
                const bool lt2 = (d < b2) || (d == b2 && ci < i2);
                const float n1 = lt0 ? b0 : (lt1 ? d : b1);
                const int  ni1 = lt0 ? i0 : (lt1 ? ci : i1);
                const float n2 = lt1 ? b1 : (lt2 ? d : b2);
                const int  ni2 = lt1 ? i1 : (lt2 ? ci : i2);
                b0 = lt0 ? d : b0;  i0 = lt0 ? ci : i0;
                b1 = n1; i1 = ni1;
                b2 = n2; i2 = ni2;
            }
        }
        float w0 = 1.0f / (b0 + EPS_D);
        float w1 = 1.0f / (b1 + EPS_D);
        float w2 = 1.0f / (b2 + EPS_D);
        const float inv = 1.0f / (w0 + w1 + w2);
        wsel[lane][0] = w0 * inv; wsel[lane][1] = w1 * inv; wsel[lane][2] = w2 * inv;
        isel[lane][0] = i0; isel[lane][1] = i1; isel[lane][2] = i2;
    }
    __syncthreads();

    // gather + weighted add: wave handles 8 u's, lane owns one float4 column
    #pragma unroll
    for (int r = 0; r < 8; ++r) {
        const int ul = wave * 8 + r;
        const float w0 = wsel[ul][0], w1 = wsel[ul][1], w2 = wsel[ul][2];
        const int a0 = isel[ul][0], a1 = isel[ul][1], a2 = isel[ul][2];
        const float4 v0 = ((const float4*)(xc + (size_t)a0 * 256))[lane];
        const float4 v1 = ((const float4*)(xc + (size_t)a1 * 256))[lane];
        const float4 v2 = ((const float4*)(xc + (size_t)a2 * 256))[lane];
        float4* op = (float4*)(out + (size_t)(blockIdx.x * 64 + ul) * 256);
        float4 o = op[lane];
        o.x += w0 * v0.x + w1 * v1.x + w2 * v2.x;
        o.y += w0 * v0.y + w1 * v1.y + w2 * v2.y;
        o.z += w0 * v0.z + w1 * v1.z + w2 * v2.z;
        o.w += w0 * v0.w + w1 * v1.w + w2 * v2.w;
        op[lane] = o;
    }
}

// ---------------------------------------------------------------------------
extern "C" void kernel_launch(void* const* d_in, const int* in_sizes, int n_in,
                              void* d_out, int out_size, void* d_ws, size_t ws_size,
                              hipStream_t stream)
{
    const float* x_feat   = (const float*)d_in[0];
    const float* x_pos    = (const float*)d_in[1];
    const float* xup_feat = (const float*)d_in[2];
    const float* xup_pos  = (const float*)d_in[3];
    const float* g1       = (const float*)d_in[4];
    const float* b1       = (const float*)d_in[5];
    const float* W        = (const float*)d_in[6];
    const float* bb       = (const float*)d_in[7];
    const float* g2       = (const float*)d_in[8];
    const float* b2       = (const float*)d_in[9];
    const float* W_up     = (const float*)d_in[10];
    const float* b_up     = (const float*)d_in[11];

    float* out = (float*)d_out;
    char*  ws  = (char*)d_ws;

    float* xc  = (float*)(ws + XC_OFF);
    float* mu  = (float*)(ws + MU_OFF);
    float* rs  = (float*)(ws + RS_OFF);
    float4* cp = (float4*)(ws + CP_OFF);
    unsigned short* wth  = (unsigned short*)(ws + WTH_OFF);
    unsigned short* wtl  = (unsigned short*)(ws + WTL_OFF);
    unsigned short* wuth = (unsigned short*)(ws + WUTH_OFF);
    unsigned short* wutl = (unsigned short*)(ws + WUTL_OFF);

    prep_kernel<<<352, 256, 0, stream>>>(x_feat, xup_feat, x_pos, W, W_up,
                                         mu, rs, cp, wth, wtl, wuth, wutl);
    gemm_kernel<<<320, 256, 0, stream>>>(xup_feat, x_feat, mu, rs,
                                         g2, b2, g1, b1,
                                         wuth, wutl, wth, wtl,
                                         b_up, bb, out, xc);
    topk_kernel<<<256, 512, 0, stream>>>(cp, xup_pos, xc, out);
}

// Round 4
// 173.760 us; speedup vs baseline: 1.6319x; 1.1635x over previous
//
#include <hip/hip_runtime.h>

#define EPS_LN 1e-5f
#define EPS_D  1e-8f

typedef __attribute__((ext_vector_type(8))) short s16x8;
typedef __attribute__((ext_vector_type(4))) float f32x4;

// ---------------- ws layout (bytes) ----------------
#define XC_OFF     0u         // 4096*256*4 = 4194304
#define MU_OFF     4194304u   // 20480*4
#define RS_OFF     4276224u   // 20480*4
#define WTH_OFF    4358144u   // 256*256*2
#define WTL_OFF    4489216u
#define WUTH_OFF   4620288u
#define WUTL_OFF   4751360u
#define CPS_OFF    4882432u   // 4096*16   (sorted x,y,z,|c|^2)
#define IDXS_OFF   4947968u   // 4096*4    (sorted -> original index)
#define CST_OFF    4964352u   // 513*4     (cellStart)

// ---------------------------------------------------------------------------
// prep: (a) LN row stats for fine(16384)+coarse(4096) rows
//       (b) W, W_up -> transposed bf16 hi/lo planes (truncation split)
// ---------------------------------------------------------------------------
__global__ __launch_bounds__(256) void prep_kernel(
    const float* __restrict__ x_feat, const float* __restrict__ xup_feat,
    const float* __restrict__ W, const float* __restrict__ W_up,
    float* __restrict__ mu, float* __restrict__ rs,
    unsigned short* __restrict__ wth, unsigned short* __restrict__ wtl,
    unsigned short* __restrict__ wuth, unsigned short* __restrict__ wutl)
{
    const int bid = blockIdx.x, tid = threadIdx.x;
    const int lane = tid & 63, wave = tid >> 6;

    if (bid < 320) {
        for (int r = bid * 4 + wave; r < 20480; r += 1280) {
            const float* src = (r < 16384) ? (xup_feat + (size_t)r * 256)
                                           : (x_feat + (size_t)(r - 16384) * 256);
            const float4 v = ((const float4*)src)[lane];
            float s  = v.x + v.y + v.z + v.w;
            float ss = v.x*v.x + v.y*v.y + v.z*v.z + v.w*v.w;
            #pragma unroll
            for (int off = 1; off < 64; off <<= 1) {
                s  += __shfl_xor(s,  off);
                ss += __shfl_xor(ss, off);
            }
            if (lane == 0) {
                const float m   = s * (1.0f / 256.0f);
                const float var = ss * (1.0f / 256.0f) - m * m;
                mu[r] = m;
                rs[r] = rsqrtf(var + EPS_LN);
            }
        }
    } else {
        const int mb = bid - 320;
        const float* src = (mb < 8) ? W : W_up;
        unsigned short* dh = (mb < 8) ? wth : wuth;
        unsigned short* dl = (mb < 8) ? wtl : wutl;
        const int k  = (mb & 7) * 32 + (tid >> 3);
        const int n0 = (tid & 7) * 32;
        for (int i = 0; i < 32; i += 4) {
            const float4 v = *(const float4*)&src[(size_t)k * 256 + n0 + i];
            const float vv[4] = { v.x, v.y, v.z, v.w };
            #pragma unroll
            for (int c = 0; c < 4; ++c) {
                const unsigned ua = __float_as_uint(vv[c]);
                const unsigned hb = ua & 0xFFFF0000u;
                const float rr = vv[c] - __uint_as_float(hb);
                const size_t o = (size_t)(n0 + i + c) * 256 + k;
                dh[o] = (unsigned short)(ua >> 16);
                dl[o] = (unsigned short)(__float_as_uint(rr) >> 16);
            }
        }
    }
}

// ---------------------------------------------------------------------------
// grid_kernel: bin 4096 coarse points into an 8^3 grid (cell size 0.125).
// One block, 1024 threads: count -> scan -> scatter.
// Outputs: cellStart[513], cps[4096] = (x,y,z,|c|^2) sorted, idxs[4096].
// ---------------------------------------------------------------------------
__device__ __forceinline__ int cell_of(float px, float py, float pz) {
    int cx = (int)(px * 8.0f); cx = cx < 0 ? 0 : (cx > 7 ? 7 : cx);
    int cy = (int)(py * 8.0f); cy = cy < 0 ? 0 : (cy > 7 ? 7 : cy);
    int cz = (int)(pz * 8.0f); cz = cz < 0 ? 0 : (cz > 7 ? 7 : cz);
    return (cz * 8 + cy) * 8 + cx;
}

__global__ __launch_bounds__(1024) void grid_kernel(
    const float* __restrict__ x_pos,
    float4* __restrict__ cps, int* __restrict__ idxs, int* __restrict__ cellStart)
{
    __shared__ int cnt[512];
    __shared__ int ofs[512];
    __shared__ int wsum[8];

    const int tid = threadIdx.x, lane = tid & 63;
    if (tid < 512) cnt[tid] = 0;
    __syncthreads();

    for (int i = tid; i < 4096; i += 1024) {
        const int c = cell_of(x_pos[i*3+0], x_pos[i*3+1], x_pos[i*3+2]);
        atomicAdd(&cnt[c], 1);
    }
    __syncthreads();

    int v = 0, incl = 0;
    if (tid < 512) {
        v = cnt[tid];
        incl = v;
        #pragma unroll
        for (int off = 1; off < 64; off <<= 1) {
            const int t = __shfl_up(incl, off);
            if (lane >= off) incl += t;
        }
        if (lane == 63) wsum[tid >> 6] = incl;
    }
    __syncthreads();
    if (tid == 0) {
        int run = 0;
        for (int w = 0; w < 8; ++w) { const int t = wsum[w]; wsum[w] = run; run += t; }
    }
    __syncthreads();
    if (tid < 512) {
        const int excl = incl - v + wsum[tid >> 6];
        ofs[tid] = excl;
        cellStart[tid] = excl;
    }
    if (tid == 0) cellStart[512] = 4096;
    __syncthreads();

    for (int i = tid; i < 4096; i += 1024) {
        const float px = x_pos[i*3+0], py = x_pos[i*3+1], pz = x_pos[i*3+2];
        const int c = cell_of(px, py, pz);
        const int p = atomicAdd(&ofs[c], 1);
        cps[p] = make_float4(px, py, pz, px*px + py*py + pz*pz);
        idxs[p] = i;
    }
}

// ---------------------------------------------------------------------------
// gemm: Y = LN(X) @ Wt^T + bias via bf16x2 split (hh + hl + lh MFMAs).
// Register-lean: A-fragments built one mf at a time.
// ---------------------------------------------------------------------------
__global__ __launch_bounds__(256) void gemm_kernel(
    const float* __restrict__ Xf, const float* __restrict__ Xc,
    const float* __restrict__ mu, const float* __restrict__ rs,
    const float* __restrict__ g2, const float* __restrict__ b2,
    const float* __restrict__ g1, const float* __restrict__ b1,
    const unsigned short* __restrict__ wuth, const unsigned short* __restrict__ wutl,
    const unsigned short* __restrict__ wth,  const unsigned short* __restrict__ wtl,
    const float* __restrict__ b_up, const float* __restrict__ bb,
    float* __restrict__ outF, float* __restrict__ outC)
{
    const int bid = blockIdx.x;
    const float *X, *gg, *bt, *bias; const unsigned short *BH, *BL; float* OUT;
    int row0, col0, statoff;
    if (bid < 256) {
        X = Xf; gg = g2; bt = b2; BH = wuth; BL = wutl; bias = b_up; OUT = outF;
        row0 = (bid >> 1) * 128; col0 = (bid & 1) * 128; statoff = 0;
    } else {
        const int id = bid - 256;
        X = Xc; gg = g1; bt = b1; BH = wth; BL = wtl; bias = bb; OUT = outC;
        row0 = (id >> 1) * 128; col0 = (id & 1) * 128; statoff = 16384;
    }

    const int lane = threadIdx.x & 63;
    const int wave = threadIdx.x >> 6;
    const int wr = wave >> 1, wc = wave & 1;
    const int lm = lane & 15, lk = lane >> 4;

    int arow[4]; float amu[4], ars[4];
    #pragma unroll
    for (int mf = 0; mf < 4; ++mf) {
        arow[mf] = row0 + wr * 64 + mf * 16 + lm;
        amu[mf] = mu[statoff + arow[mf]];
        ars[mf] = rs[statoff + arow[mf]];
    }
    int ncol[4]; float bv[4];
    #pragma unroll
    for (int nf = 0; nf < 4; ++nf) {
        ncol[nf] = col0 + wc * 64 + nf * 16 + lm;
        bv[nf] = bias[ncol[nf]];
    }

    f32x4 acc[4][4];
    #pragma unroll
    for (int mf = 0; mf < 4; ++mf)
        #pragma unroll
        for (int nf = 0; nf < 4; ++nf)
            acc[mf][nf] = (f32x4){0.0f, 0.0f, 0.0f, 0.0f};

    for (int k0 = 0; k0 < 256; k0 += 32) {
        const int kb = k0 + lk * 8;

        s16x8 bh[4], bl[4];
        #pragma unroll
        for (int nf = 0; nf < 4; ++nf) {
            const size_t o = (size_t)ncol[nf] * 256 + kb;
            bh[nf] = *(const s16x8*)(BH + o);
            bl[nf] = *(const s16x8*)(BL + o);
        }

        const float4 gq0 = *(const float4*)(gg + kb);
        const float4 gq1 = *(const float4*)(gg + kb + 4);
        const float4 bq0 = *(const float4*)(bt + kb);
        const float4 bq1 = *(const float4*)(bt + kb + 4);
        const float gv[8] = { gq0.x, gq0.y, gq0.z, gq0.w, gq1.x, gq1.y, gq1.z, gq1.w };
        const float bw[8] = { bq0.x, bq0.y, bq0.z, bq0.w, bq1.x, bq1.y, bq1.z, bq1.w };

        #pragma unroll
        for (int mf = 0; mf < 4; ++mf) {
            const float* pa = X + (size_t)arow[mf] * 256 + kb;
            const float4 x0 = *(const float4*)pa;
            const float4 x1 = *(const float4*)(pa + 4);
            const float xs[8] = { x0.x, x0.y, x0.z, x0.w, x1.x, x1.y, x1.z, x1.w };
            s16x8 ah, al;
            #pragma unroll
            for (int j = 0; j < 8; ++j) {
                const float sj = ars[mf] * gv[j];
                const float tj = fmaf(-amu[mf], sj, bw[j]);
                const float a  = fmaf(xs[j], sj, tj);
                const unsigned ua = __float_as_uint(a);
                const unsigned hb = ua & 0xFFFF0000u;
                const float rr = a - __uint_as_float(hb);
                ah[j] = (short)(ua >> 16);
                al[j] = (short)(__float_as_uint(rr) >> 16);
            }
            #pragma unroll
            for (int nf = 0; nf < 4; ++nf) {
                acc[mf][nf] = __builtin_amdgcn_mfma_f32_16x16x32_bf16(ah, bh[nf], acc[mf][nf], 0, 0, 0);
                acc[mf][nf] = __builtin_amdgcn_mfma_f32_16x16x32_bf16(ah, bl[nf], acc[mf][nf], 0, 0, 0);
                acc[mf][nf] = __builtin_amdgcn_mfma_f32_16x16x32_bf16(al, bh[nf], acc[mf][nf], 0, 0, 0);
            }
        }
    }

    #pragma unroll
    for (int mf = 0; mf < 4; ++mf) {
        #pragma unroll
        for (int q = 0; q < 4; ++q) {
            const size_t ro = (size_t)(row0 + wr * 64 + mf * 16 + lk * 4 + q) * 256;
            #pragma unroll
            for (int nf = 0; nf < 4; ++nf)
                OUT[ro + ncol[nf]] = acc[mf][nf][q] + bv[nf];
        }
    }
}

// ---------------------------------------------------------------------------
// topk: grid-accelerated 3-NN. Block = 512 thr (8 waves), 64 u's per block
// (u = bid*64 + lane). Wave w scans cells {w, w+8, w+16, w+24} of each u's
// 27-cell neighborhood; LDS merge; exact boundary-guarantee check with
// brute-force fallback; inverse-distance weights; gather + add.
// ---------------------------------------------------------------------------
#define BIGD 3.402823466e+38f

__device__ __forceinline__ void ins3(float d, int p,
    float& b0, float& b1, float& b2, int& p0, int& p1, int& p2)
{
    const bool lt0 = d < b0, lt1 = d < b1, lt2 = d < b2;
    const float n1 = lt0 ? b0 : (lt1 ? d : b1);
    const int   q1 = lt0 ? p0 : (lt1 ? p : p1);
    const float n2 = lt1 ? b1 : (lt2 ? d : b2);
    const int   q2 = lt1 ? p1 : (lt2 ? p : p2);
    b0 = lt0 ? d : b0;  p0 = lt0 ? p : p0;
    b1 = n1; p1 = q1;
    b2 = n2; p2 = q2;
}

__global__ __launch_bounds__(512) void topk_kernel(
    const float4* __restrict__ cps, const int* __restrict__ idxs,
    const int* __restrict__ cellStart,
    const float* __restrict__ xup_pos,
    const float* __restrict__ xc, float* __restrict__ out)
{
    __shared__ float pd[8][64][3];
    __shared__ int   pp[8][64][3];
    __shared__ float wsel[64][3];
    __shared__ int   isel[64][3];
    __shared__ int   cst[513];

    const int tid = threadIdx.x, lane = tid & 63, wave = tid >> 6;
    const int u = blockIdx.x * 64 + lane;

    for (int i = tid; i < 513; i += 512) cst[i] = cellStart[i];

    const float ux = xup_pos[u * 3 + 0];
    const float uy = xup_pos[u * 3 + 1];
    const float uz = xup_pos[u * 3 + 2];
    const float uu = ux * ux + uy * uy + uz * uz;
    int cx = (int)(ux * 8.0f); cx = cx < 0 ? 0 : (cx > 7 ? 7 : cx);
    int cy = (int)(uy * 8.0f); cy = cy < 0 ? 0 : (cy > 7 ? 7 : cy);
    int cz = (int)(uz * 8.0f); cz = cz < 0 ? 0 : (cz > 7 ? 7 : cz);

    __syncthreads();

    float b0 = BIGD, b1 = BIGD, b2 = BIGD;
    int p0 = 0, p1 = 0, p2 = 0;

    for (int cc = wave; cc < 27; cc += 8) {
        const int nx = cx + (cc % 3) - 1;
        const int ny = cy + ((cc / 3) % 3) - 1;
        const int nz = cz + (cc / 9) - 1;
        if ((unsigned)nx > 7u || (unsigned)ny > 7u || (unsigned)nz > 7u) continue;
        const int cell = (nz * 8 + ny) * 8 + nx;
        const int s = cst[cell], e = cst[cell + 1];
        if (s >= e) continue;
        float4 c = cps[s];
        for (int p = s; p < e; ++p) {
            const float4 nxt = (p + 1 < e) ? cps[p + 1] : c;   // 1-deep prefetch
            const float dot = ux * c.x + uy * c.y + uz * c.z;
            const float d = (uu - 2.0f * dot) + c.w;
            ins3(d, p, b0, b1, b2, p0, p1, p2);
            c = nxt;
        }
    }

    pd[wave][lane][0] = b0; pd[wave][lane][1] = b1; pd[wave][lane][2] = b2;
    pp[wave][lane][0] = p0; pp[wave][lane][1] = p1; pp[wave][lane][2] = p2;
    __syncthreads();

    if (wave == 0) {
        for (int w = 1; w < 8; ++w) {
            #pragma unroll
            for (int e = 0; e < 3; ++e)
                ins3(pd[w][lane][e], pp[w][lane][e], b0, b1, b2, p0, p1, p2);
        }

        // exact coverage guarantee: scanned region extends at least to these
        // planes; beyond them no candidate was visited. (Domain edges: no
        // points outside [0,1]^3, so clamped sides are safe.)
        const float h = 0.125f;
        float gmin = BIGD;
        if (cx > 0) gmin = fminf(gmin, ux - (float)(cx - 1) * h);
        if (cx < 7) gmin = fminf(gmin, (float)(cx + 2) * h - ux);
        if (cy > 0) gmin = fminf(gmin, uy - (float)(cy - 1) * h);
        if (cy < 7) gmin = fminf(gmin, (float)(cy + 2) * h - uy);
        if (cz > 0) gmin = fminf(gmin, uz - (float)(cz - 1) * h);
        if (cz < 7) gmin = fminf(gmin, (float)(cz + 2) * h - uz);

        if (b2 > gmin * gmin) {   // ~never taken; exact fallback
            b0 = b1 = b2 = BIGD; p0 = p1 = p2 = 0;
            for (int p = 0; p < 4096; ++p) {
                const float4 c = cps[p];
                const float dot = ux * c.x + uy * c.y + uz * c.z;
                const float d = (uu - 2.0f * dot) + c.w;
                ins3(d, p, b0, b1, b2, p0, p1, p2);
            }
        }

        float w0 = 1.0f / (b0 + EPS_D);
        float w1 = 1.0f / (b1 + EPS_D);
        float w2 = 1.0f / (b2 + EPS_D);
        const float inv = 1.0f / (w0 + w1 + w2);
        wsel[lane][0] = w0 * inv; wsel[lane][1] = w1 * inv; wsel[lane][2] = w2 * inv;
        isel[lane][0] = idxs[p0]; isel[lane][1] = idxs[p1]; isel[lane][2] = idxs[p2];
    }
    __syncthreads();

    #pragma unroll
    for (int r = 0; r < 8; ++r) {
        const int ul = wave * 8 + r;
        const float w0 = wsel[ul][0], w1 = wsel[ul][1], w2 = wsel[ul][2];
        const int a0 = isel[ul][0], a1 = isel[ul][1], a2 = isel[ul][2];
        const float4 v0 = ((const float4*)(xc + (size_t)a0 * 256))[lane];
        const float4 v1 = ((const float4*)(xc + (size_t)a1 * 256))[lane];
        const float4 v2 = ((const float4*)(xc + (size_t)a2 * 256))[lane];
        float4* op = (float4*)(out + (size_t)(blockIdx.x * 64 + ul) * 256);
        float4 o = op[lane];
        o.x += w0 * v0.x + w1 * v1.x + w2 * v2.x;
        o.y += w0 * v0.y + w1 * v1.y + w2 * v2.y;
        o.z += w0 * v0.z + w1 * v1.z + w2 * v2.z;
        o.w += w0 * v0.w + w1 * v1.w + w2 * v2.w;
        op[lane] = o;
    }
}

// ---------------------------------------------------------------------------
extern "C" void kernel_launch(void* const* d_in, const int* in_sizes, int n_in,
                              void* d_out, int out_size, void* d_ws, size_t ws_size,
                              hipStream_t stream)
{
    const float* x_feat   = (const float*)d_in[0];
    const float* x_pos    = (const float*)d_in[1];
    const float* xup_feat = (const float*)d_in[2];
    const float* xup_pos  = (const float*)d_in[3];
    const float* g1       = (const float*)d_in[4];
    const float* b1       = (const float*)d_in[5];
    const float* W        = (const float*)d_in[6];
    const float* bb       = (const float*)d_in[7];
    const float* g2       = (const float*)d_in[8];
    const float* b2       = (const float*)d_in[9];
    const float* W_up     = (const float*)d_in[10];
    const float* b_up     = (const float*)d_in[11];

    float* out = (float*)d_out;
    char*  ws  = (char*)d_ws;

    float* xc  = (float*)(ws + XC_OFF);
    float* mu  = (float*)(ws + MU_OFF);
    float* rs  = (float*)(ws + RS_OFF);
    unsigned short* wth  = (unsigned short*)(ws + WTH_OFF);
    unsigned short* wtl  = (unsigned short*)(ws + WTL_OFF);
    unsigned short* wuth = (unsigned short*)(ws + WUTH_OFF);
    unsigned short* wutl = (unsigned short*)(ws + WUTL_OFF);
    float4* cps = (float4*)(ws + CPS_OFF);
    int* idxs   = (int*)(ws + IDXS_OFF);
    int* cstart = (int*)(ws + CST_OFF);

    prep_kernel<<<336, 256, 0, stream>>>(x_feat, xup_feat, W, W_up,
                                         mu, rs, wth, wtl, wuth, wutl);
    grid_kernel<<<1, 1024, 0, stream>>>(x_pos, cps, idxs, cstart);
    gemm_kernel<<<320, 256, 0, stream>>>(xup_feat, x_feat, mu, rs,
                                         g2, b2, g1, b1,
                                         wuth, wutl, wth, wtl,
                                         b_up, bb, out, xc);
    topk_kernel<<<256, 512, 0, stream>>>(cps, idxs, cstart, xup_pos, xc, out);
}

// Round 5
// 167.335 us; speedup vs baseline: 1.6945x; 1.0384x over previous
//
#include <hip/hip_runtime.h>

#define EPS_LN 1e-5f
#define EPS_D  1e-8f
#define BIGD 3.402823466e+38f

typedef __attribute__((ext_vector_type(8))) short s16x8;
typedef __attribute__((ext_vector_type(4))) float f32x4;
typedef __attribute__((ext_vector_type(4))) unsigned short u16x4;

// ---------------- ws layout (bytes) ----------------
#define XC_OFF    0u          // 4096*256*4   coarse GEMM output
#define XH_OFF    4194304u    // 20480*256*2  x hi-plane (fine rows 0..16383, coarse +16384)
#define XL_OFF    14680064u   // 20480*256*2  x lo-plane
#define MU_OFF    25165824u   // 20480*4
#define RS_OFF    25247744u   // 20480*4
#define WGH_OFF   25329664u   // 256*256*2  (g1*W)^T hi   [n][k]
#define WGL_OFF   25460736u   //            (g1*W)^T lo
#define WUGH_OFF  25591808u   //            (g2*W_up)^T hi
#define WUGL_OFF  25722880u   //            (g2*W_up)^T lo
#define C12_OFF   25853952u   // 4*256 f32: [c1_fine, c2_fine, c1_coarse, c2_coarse]
#define CPS_OFF   25858048u   // 4096*16 sorted (x,y,z,|c|^2)
#define IDXS_OFF  25923584u   // 4096*4
#define CST_OFF   25939968u   // 513*4

// ---------------------------------------------------------------------------
// prep: role by blockIdx:
//  [0,640)   : LN row stats + raw-x truncation-split into bf16 hi/lo planes
//  [640,656) : W,W_up -> g-folded transposed hi/lo bf16 planes
//  656,657   : c1 = b_ln@W, c2 = g@W (coarse / fine)
//  658       : 8^3 grid binning of coarse points (count/scan/scatter)
// ---------------------------------------------------------------------------
__device__ __forceinline__ int cell_of(float px, float py, float pz) {
    int cx = (int)(px * 8.0f); cx = cx < 0 ? 0 : (cx > 7 ? 7 : cx);
    int cy = (int)(py * 8.0f); cy = cy < 0 ? 0 : (cy > 7 ? 7 : cy);
    int cz = (int)(pz * 8.0f); cz = cz < 0 ? 0 : (cz > 7 ? 7 : cz);
    return (cz * 8 + cy) * 8 + cx;
}

__global__ __launch_bounds__(256) void prep_kernel(
    const float* __restrict__ x_feat, const float* __restrict__ xup_feat,
    const float* __restrict__ x_pos,
    const float* __restrict__ W, const float* __restrict__ W_up,
    const float* __restrict__ g1, const float* __restrict__ b1,
    const float* __restrict__ g2, const float* __restrict__ b2,
    float* __restrict__ mu, float* __restrict__ rs,
    unsigned short* __restrict__ xh, unsigned short* __restrict__ xl,
    unsigned short* __restrict__ wgh, unsigned short* __restrict__ wgl,
    unsigned short* __restrict__ wugh, unsigned short* __restrict__ wugl,
    float* __restrict__ c12,
    float4* __restrict__ cps, int* __restrict__ idxs, int* __restrict__ cellStart)
{
    __shared__ int cnt[512];
    __shared__ int ofs[512];
    __shared__ int wpart[4];

    const int bid = blockIdx.x, tid = threadIdx.x;
    const int lane = tid & 63, wave = tid >> 6;

    if (bid < 640) {
        // ---- LN stats + split (memory-bound streaming) ----
        #pragma unroll
        for (int rr = 0; rr < 8; ++rr) {
            const int r = bid * 32 + wave * 8 + rr;
            const float* src = (r < 16384) ? (xup_feat + (size_t)r * 256)
                                           : (x_feat + (size_t)(r - 16384) * 256);
            const float4 v = ((const float4*)src)[lane];
            float s  = v.x + v.y + v.z + v.w;
            float ss = v.x*v.x + v.y*v.y + v.z*v.z + v.w*v.w;
            #pragma unroll
            for (int off = 1; off < 64; off <<= 1) {
                s  += __shfl_xor(s,  off);
                ss += __shfl_xor(ss, off);
            }
            if (lane == 0) {
                const float m   = s * (1.0f / 256.0f);
                const float var = ss * (1.0f / 256.0f) - m * m;
                mu[r] = m;
                rs[r] = rsqrtf(var + EPS_LN);
            }
            const float vv[4] = { v.x, v.y, v.z, v.w };
            u16x4 hv, lv;
            #pragma unroll
            for (int c = 0; c < 4; ++c) {
                const unsigned ua = __float_as_uint(vv[c]);
                hv[c] = (unsigned short)(ua >> 16);
                const float lo = vv[c] - __uint_as_float(ua & 0xFFFF0000u);
                lv[c] = (unsigned short)(__float_as_uint(lo) >> 16);
            }
            *(u16x4*)&xh[(size_t)r * 256 + lane * 4] = hv;
            *(u16x4*)&xl[(size_t)r * 256 + lane * 4] = lv;
        }
    } else if (bid < 656) {
        // ---- g-folded transposed weight planes ----
        const int mb = bid - 640;
        const float* src = (mb < 8) ? W : W_up;
        const float* g   = (mb < 8) ? g1 : g2;
        unsigned short* dh = (mb < 8) ? wgh : wugh;
        unsigned short* dl = (mb < 8) ? wgl : wugl;
        const int n  = (mb & 7) * 32 + (tid >> 3);
        const int kc = (tid & 7) * 32;
        for (int kk = 0; kk < 32; kk += 4) {
            u16x4 hv, lv;
            #pragma unroll
            for (int c = 0; c < 4; ++c) {
                const int k = kc + kk + c;
                const float wv = g[k] * src[(size_t)k * 256 + n];
                const unsigned ua = __float_as_uint(wv);
                hv[c] = (unsigned short)(ua >> 16);
                const float lo = wv - __uint_as_float(ua & 0xFFFF0000u);
                lv[c] = (unsigned short)(__float_as_uint(lo) >> 16);
            }
            *(u16x4*)&dh[(size_t)n * 256 + kc + kk] = hv;
            *(u16x4*)&dl[(size_t)n * 256 + kc + kk] = lv;
        }
    } else if (bid < 658) {
        // ---- c1 = b_ln@W, c2 = g@W ----
        const bool fine = (bid == 657);
        const float* src = fine ? W_up : W;
        const float* g   = fine ? g2 : g1;
        const float* bln = fine ? b2 : b1;
        float* c1 = c12 + (fine ? 0 : 512);
        float* c2 = c12 + (fine ? 256 : 768);
        float a1 = 0.0f, a2 = 0.0f;
        for (int k = 0; k < 256; ++k) {
            const float wv = src[(size_t)k * 256 + tid];
            a1 = fmaf(bln[k], wv, a1);
            a2 = fmaf(g[k],   wv, a2);
        }
        c1[tid] = a1;
        c2[tid] = a2;
    } else {
        // ---- grid binning: count -> scan -> scatter (256 threads) ----
        cnt[tid] = 0; cnt[tid + 256] = 0;
        __syncthreads();
        for (int i = tid; i < 4096; i += 256) {
            const int c = cell_of(x_pos[i*3+0], x_pos[i*3+1], x_pos[i*3+2]);
            atomicAdd(&cnt[c], 1);
        }
        __syncthreads();
        // scan over 512 cells: wave w owns [w*128, w*128+128), lane owns 2
        const int base = wave * 128 + lane * 2;
        const int a = cnt[base], b = cnt[base + 1];
        const int p = a + b;
        int incl = p;
        #pragma unroll
        for (int off = 1; off < 64; off <<= 1) {
            const int t = __shfl_up(incl, off);
            if (lane >= off) incl += t;
        }
        if (lane == 63) wpart[wave] = incl;
        __syncthreads();
        int woff = 0;
        for (int w = 0; w < 4; ++w) if (w < wave) woff += wpart[w];
        const int e0 = woff + (incl - p);
        ofs[base] = e0;          ofs[base + 1] = e0 + a;
        cellStart[base] = e0;    cellStart[base + 1] = e0 + a;
        if (tid == 0) cellStart[512] = 4096;
        __syncthreads();
        for (int i = tid; i < 4096; i += 256) {
            const float px = x_pos[i*3+0], py = x_pos[i*3+1], pz = x_pos[i*3+2];
            const int c = cell_of(px, py, pz);
            const int pos = atomicAdd(&ofs[c], 1);
            cps[pos] = make_float4(px, py, pz, px*px + py*py + pz*pz);
            idxs[pos] = i;
        }
    }
}

// ---------------------------------------------------------------------------
// gemm: S = x @ Wg via split-bf16 (hh+hl+lh), pure loads+MFMA inner loop.
// Epilogue: y = rs*S + (c1 - mu*rs*c2) + bias   (LN hoisted out as affine).
// blocks 0..255 fine (-> d_out), 256..319 coarse (-> xc).
// ---------------------------------------------------------------------------
__global__ __launch_bounds__(256) void gemm_kernel(
    const unsigned short* __restrict__ xh, const unsigned short* __restrict__ xl,
    const float* __restrict__ mu, const float* __restrict__ rs,
    const unsigned short* __restrict__ wgh, const unsigned short* __restrict__ wgl,
    const unsigned short* __restrict__ wugh, const unsigned short* __restrict__ wugl,
    const float* __restrict__ c12,
    const float* __restrict__ b_up, const float* __restrict__ bb,
    float* __restrict__ outF, float* __restrict__ outC)
{
    const int bid = blockIdx.x;
    const unsigned short *BH, *BL; const float *c1, *c2, *bias; float* OUT;
    int row0, col0, statbase;
    if (bid < 256) {
        BH = wugh; BL = wugl; c1 = c12; c2 = c12 + 256; bias = b_up; OUT = outF;
        row0 = (bid >> 1) * 128; col0 = (bid & 1) * 128; statbase = 0;
    } else {
        const int id = bid - 256;
        BH = wgh; BL = wgl; c1 = c12 + 512; c2 = c12 + 768; bias = bb; OUT = outC;
        row0 = (id >> 1) * 128; col0 = (id & 1) * 128; statbase = 16384;
    }

    const int lane = threadIdx.x & 63;
    const int wave = threadIdx.x >> 6;
    const int wr = wave >> 1, wc = wave & 1;
    const int lm = lane & 15, lk = lane >> 4;

    int arow[4];
    #pragma unroll
    for (int mf = 0; mf < 4; ++mf)
        arow[mf] = statbase + row0 + wr * 64 + mf * 16 + lm;

    int ncol[4]; float c1v[4], c2v[4], bv[4];
    #pragma unroll
    for (int nf = 0; nf < 4; ++nf) {
        ncol[nf] = col0 + wc * 64 + nf * 16 + lm;
        c1v[nf] = c1[ncol[nf]];
        c2v[nf] = c2[ncol[nf]];
        bv[nf]  = bias[ncol[nf]];
    }

    f32x4 acc[4][4];
    #pragma unroll
    for (int mf = 0; mf < 4; ++mf)
        #pragma unroll
        for (int nf = 0; nf < 4; ++nf)
            acc[mf][nf] = (f32x4){0.0f, 0.0f, 0.0f, 0.0f};

    for (int k0 = 0; k0 < 256; k0 += 32) {
        const int kb = k0 + lk * 8;

        s16x8 bh[4], bl[4], ah[4], al[4];
        #pragma unroll
        for (int nf = 0; nf < 4; ++nf) {
            const size_t o = (size_t)ncol[nf] * 256 + kb;
            bh[nf] = *(const s16x8*)(BH + o);
            bl[nf] = *(const s16x8*)(BL + o);
        }
        #pragma unroll
        for (int mf = 0; mf < 4; ++mf) {
            const size_t o = (size_t)arow[mf] * 256 + kb;
            ah[mf] = *(const s16x8*)(xh + o);
            al[mf] = *(const s16x8*)(xl + o);
        }

        #pragma unroll
        for (int mf = 0; mf < 4; ++mf)
            #pragma unroll
            for (int nf = 0; nf < 4; ++nf) {
                acc[mf][nf] = __builtin_amdgcn_mfma_f32_16x16x32_bf16(ah[mf], bh[nf], acc[mf][nf], 0, 0, 0);
                acc[mf][nf] = __builtin_amdgcn_mfma_f32_16x16x32_bf16(ah[mf], bl[nf], acc[mf][nf], 0, 0, 0);
                acc[mf][nf] = __builtin_amdgcn_mfma_f32_16x16x32_bf16(al[mf], bh[nf], acc[mf][nf], 0, 0, 0);
            }
    }

    #pragma unroll
    for (int mf = 0; mf < 4; ++mf) {
        #pragma unroll
        for (int q = 0; q < 4; ++q) {
            const int orow = row0 + wr * 64 + mf * 16 + lk * 4 + q;
            const float m = mu[statbase + orow];
            const float s = rs[statbase + orow];
            const float ms = -m * s;
            #pragma unroll
            for (int nf = 0; nf < 4; ++nf)
                OUT[(size_t)orow * 256 + ncol[nf]] =
                    fmaf(s, acc[mf][nf][q], fmaf(ms, c2v[nf], c1v[nf]) + bv[nf]);
        }
    }
}

// ---------------------------------------------------------------------------
// topk: grid-accelerated 3-NN (unchanged from round 4, passing).
// ---------------------------------------------------------------------------
__device__ __forceinline__ void ins3(float d, int p,
    float& b0, float& b1, float& b2, int& p0, int& p1, int& p2)
{
    const bool lt0 = d < b0, lt1 = d < b1, lt2 = d < b2;
    const float n1 = lt0 ? b0 : (lt1 ? d : b1);
    const int   q1 = lt0 ? p0 : (lt1 ? p : p1);
    const float n2 = lt1 ? b1 : (lt2 ? d : b2);
    const int   q2 = lt1 ? p1 : (lt2 ? p : p2);
    b0 = lt0 ? d : b0;  p0 = lt0 ? p : p0;
    b1 = n1; p1 = q1;
    b2 = n2; p2 = q2;
}

__global__ __launch_bounds__(512) void topk_kernel(
    const float4* __restrict__ cps, const int* __restrict__ idxs,
    const int* __restrict__ cellStart,
    const float* __restrict__ xup_pos,
    const float* __restrict__ xc, float* __restrict__ out)
{
    __shared__ float pd[8][64][3];
    __shared__ int   pp[8][64][3];
    __shared__ float wsel[64][3];
    __shared__ int   isel[64][3];
    __shared__ int   cst[513];

    const int tid = threadIdx.x, lane = tid & 63, wave = tid >> 6;
    const int u = blockIdx.x * 64 + lane;

    for (int i = tid; i < 513; i += 512) cst[i] = cellStart[i];

    const float ux = xup_pos[u * 3 + 0];
    const float uy = xup_pos[u * 3 + 1];
    const float uz = xup_pos[u * 3 + 2];
    const float uu = ux * ux + uy * uy + uz * uz;
    int cx = (int)(ux * 8.0f); cx = cx < 0 ? 0 : (cx > 7 ? 7 : cx);
    int cy = (int)(uy * 8.0f); cy = cy < 0 ? 0 : (cy > 7 ? 7 : cy);
    int cz = (int)(uz * 8.0f); cz = cz < 0 ? 0 : (cz > 7 ? 7 : cz);

    __syncthreads();

    float b0 = BIGD, b1 = BIGD, b2 = BIGD;
    int p0 = 0, p1 = 0, p2 = 0;

    for (int cc = wave; cc < 27; cc += 8) {
        const int nx = cx + (cc % 3) - 1;
        const int ny = cy + ((cc / 3) % 3) - 1;
        const int nz = cz + (cc / 9) - 1;
        if ((unsigned)nx > 7u || (unsigned)ny > 7u || (unsigned)nz > 7u) continue;
        const int cell = (nz * 8 + ny) * 8 + nx;
        const int s = cst[cell], e = cst[cell + 1];
        if (s >= e) continue;
        float4 c = cps[s];
        for (int p = s; p < e; ++p) {
            const float4 nxt = (p + 1 < e) ? cps[p + 1] : c;
            const float dot = ux * c.x + uy * c.y + uz * c.z;
            const float d = (uu - 2.0f * dot) + c.w;
            ins3(d, p, b0, b1, b2, p0, p1, p2);
            c = nxt;
        }
    }

    pd[wave][lane][0] = b0; pd[wave][lane][1] = b1; pd[wave][lane][2] = b2;
    pp[wave][lane][0] = p0; pp[wave][lane][1] = p1; pp[wave][lane][2] = p2;
    __syncthreads();

    if (wave == 0) {
        for (int w = 1; w < 8; ++w) {
            #pragma unroll
            for (int e = 0; e < 3; ++e)
                ins3(pd[w][lane][e], pp[w][lane][e], b0, b1, b2, p0, p1, p2);
        }

        const float h = 0.125f;
        float gmin = BIGD;
        if (cx > 0) gmin = fminf(gmin, ux - (float)(cx - 1) * h);
        if (cx < 7) gmin = fminf(gmin, (float)(cx + 2) * h - ux);
        if (cy > 0) gmin = fminf(gmin, uy - (float)(cy - 1) * h);
        if (cy < 7) gmin = fminf(gmin, (float)(cy + 2) * h - uy);
        if (cz > 0) gmin = fminf(gmin, uz - (float)(cz - 1) * h);
        if (cz < 7) gmin = fminf(gmin, (float)(cz + 2) * h - uz);

        if (b2 > gmin * gmin) {
            b0 = b1 = b2 = BIGD; p0 = p1 = p2 = 0;
            for (int p = 0; p < 4096; ++p) {
                const float4 c = cps[p];
                const float dot = ux * c.x + uy * c.y + uz * c.z;
                const float d = (uu - 2.0f * dot) + c.w;
                ins3(d, p, b0, b1, b2, p0, p1, p2);
            }
        }

        float w0 = 1.0f / (b0 + EPS_D);
        float w1 = 1.0f / (b1 + EPS_D);
        float w2 = 1.0f / (b2 + EPS_D);
        const float inv = 1.0f / (w0 + w1 + w2);
        wsel[lane][0] = w0 * inv; wsel[lane][1] = w1 * inv; wsel[lane][2] = w2 * inv;
        isel[lane][0] = idxs[p0]; isel[lane][1] = idxs[p1]; isel[lane][2] = idxs[p2];
    }
    __syncthreads();

    #pragma unroll
    for (int r = 0; r < 8; ++r) {
        const int ul = wave * 8 + r;
        const float w0 = wsel[ul][0], w1 = wsel[ul][1], w2 = wsel[ul][2];
        const int a0 = isel[ul][0], a1 = isel[ul][1], a2 = isel[ul][2];
        const float4 v0 = ((const float4*)(xc + (size_t)a0 * 256))[lane];
        const float4 v1 = ((const float4*)(xc + (size_t)a1 * 256))[lane];
        const float4 v2 = ((const float4*)(xc + (size_t)a2 * 256))[lane];
        float4* op = (float4*)(out + (size_t)(blockIdx.x * 64 + ul) * 256);
        float4 o = op[lane];
        o.x += w0 * v0.x + w1 * v1.x + w2 * v2.x;
        o.y += w0 * v0.y + w1 * v1.y + w2 * v2.y;
        o.z += w0 * v0.z + w1 * v1.z + w2 * v2.z;
        o.w += w0 * v0.w + w1 * v1.w + w2 * v2.w;
        op[lane] = o;
    }
}

// ---------------------------------------------------------------------------
extern "C" void kernel_launch(void* const* d_in, const int* in_sizes, int n_in,
                              void* d_out, int out_size, void* d_ws, size_t ws_size,
                              hipStream_t stream)
{
    const float* x_feat   = (const float*)d_in[0];
    const float* x_pos    = (const float*)d_in[1];
    const float* xup_feat = (const float*)d_in[2];
    const float* xup_pos  = (const float*)d_in[3];
    const float* g1       = (const float*)d_in[4];
    const float* b1       = (const float*)d_in[5];
    const float* W        = (const float*)d_in[6];
    const float* bb       = (const float*)d_in[7];
    const float* g2       = (const float*)d_in[8];
    const float* b2       = (const float*)d_in[9];
    const float* W_up     = (const float*)d_in[10];
    const float* b_up     = (const float*)d_in[11];

    float* out = (float*)d_out;
    char*  ws  = (char*)d_ws;

    float* xc  = (float*)(ws + XC_OFF);
    unsigned short* xh   = (unsigned short*)(ws + XH_OFF);
    unsigned short* xl   = (unsigned short*)(ws + XL_OFF);
    float* mu  = (float*)(ws + MU_OFF);
    float* rs  = (float*)(ws + RS_OFF);
    unsigned short* wgh  = (unsigned short*)(ws + WGH_OFF);
    unsigned short* wgl  = (unsigned short*)(ws + WGL_OFF);
    unsigned short* wugh = (unsigned short*)(ws + WUGH_OFF);
    unsigned short* wugl = (unsigned short*)(ws + WUGL_OFF);
    float* c12 = (float*)(ws + C12_OFF);
    float4* cps = (float4*)(ws + CPS_OFF);
    int* idxs   = (int*)(ws + IDXS_OFF);
    int* cstart = (int*)(ws + CST_OFF);

    prep_kernel<<<659, 256, 0, stream>>>(x_feat, xup_feat, x_pos, W, W_up,
                                         g1, b1, g2, b2,
                                         mu, rs, xh, xl,
                                         wgh, wgl, wugh, wugl,
                                         c12, cps, idxs, cstart);
    gemm_kernel<<<320, 256, 0, stream>>>(xh, xl, mu, rs,
                                         wgh, wgl, wugh, wugl,
                                         c12, b_up, bb, out, xc);
    topk_kernel<<<256, 512, 0, stream>>>(cps, idxs, cstart, xup_pos, xc, out);
}